// Round 4
// baseline (7058.206 us; speedup 1.0000x reference)
//
#include <hip/hip_runtime.h>

#define T_DIM 256
#define B_DIM 128
#define F_DIM 1024
#define G_DIM 4096
#define NWGS  256

typedef short bf8  __attribute__((ext_vector_type(8)));
typedef float f32x4 __attribute__((ext_vector_type(4)));
typedef unsigned long long u64;

// ---- ws layout (bytes) ----
#define OFF_FLAGS 0ull
#define OFF_WIP   4096ull
#define SZ_WPACK  (8ull*1024*1024)        // 256nt * 32kt * 64lane * 8 * 2B
#define OFF_WHP   (OFF_WIP + SZ_WPACK)
#define OFF_XPK   (OFF_WHP + SZ_WPACK)    // 256t * 32kt * 8mt * 64 * 8 * 2B = 64 MB
#define SZ_XPK    (64ull*1024*1024)
#define OFF_HP    (OFF_XPK + SZ_XPK)      // 2 * 128*1024 * 2B = 512 KB
#define WS_NEED   (OFF_HP + 2ull*131072ull*2ull)

__device__ __forceinline__ unsigned short f2bf(float v) {
  union { float f; unsigned int u; } c; c.f = v;
  unsigned int u = c.u;
  return (unsigned short)((u + 0x7fffu + ((u >> 16) & 1u)) >> 16);  // RNE
}
__device__ __forceinline__ float sigm(float x)  { return 1.f / (1.f + __expf(-x)); }
__device__ __forceinline__ float tanh_(float x) { return 1.f - 2.f / (1.f + __expf(2.f * x)); }

// ---- pack W (fp32 F x 4F) -> MFMA-B frag order bf16: frag idx (nt*32+kt)*64+lane ----
__global__ __launch_bounds__(256) void pack_w(const float* __restrict__ Wi,
                                              const float* __restrict__ Wh,
                                              unsigned short* __restrict__ wip,
                                              unsigned short* __restrict__ whp) {
  int gid = blockIdx.x * 256 + threadIdx.x;
  const float* src = (gid >= 524288) ? Wh : Wi;
  unsigned short* dst = (gid >= 524288) ? whp : wip;
  int r  = gid & 524287;
  int nt = r >> 11;
  int kt = (r >> 6) & 31;
  int l  = r & 63;
  int col = nt * 16 + (l & 15);
  int k0  = kt * 32 + ((l >> 4) << 3);
  bf8 v8;
#pragma unroll
  for (int j = 0; j < 8; ++j)
    v8[j] = (short)f2bf(src[(size_t)(k0 + j) * G_DIM + col]);
  *reinterpret_cast<bf8*>(dst + (size_t)r * 8) = v8;
}

// ---- pack all x -> A-frag order [t][kt][mt][lane][8] ----
__global__ __launch_bounds__(256) void pack_x(const float* __restrict__ x,
                                              unsigned short* __restrict__ xpk) {
  int gid = blockIdx.x * 256 + threadIdx.x;   // T*B*128 = 4,194,304
  int fb = gid & 127;
  int b  = (gid >> 7) & 127;
  int t  = gid >> 14;
  const float* s = x + ((size_t)(t * B_DIM + b)) * F_DIM + fb * 8;
  float4 v0 = *reinterpret_cast<const float4*>(s);
  float4 v1 = *reinterpret_cast<const float4*>(s + 4);
  int kt = fb >> 2, j4 = fb & 3, mt = b >> 4;
  int lane2 = (b & 15) | (j4 << 4);
  bf8 o;
  o[0] = (short)f2bf(v0.x); o[1] = (short)f2bf(v0.y);
  o[2] = (short)f2bf(v0.z); o[3] = (short)f2bf(v0.w);
  o[4] = (short)f2bf(v1.x); o[5] = (short)f2bf(v1.y);
  o[6] = (short)f2bf(v1.z); o[7] = (short)f2bf(v1.w);
  *reinterpret_cast<bf8*>(xpk + ((size_t)(((t * 32 + kt) * 8 + mt) * 64) + lane2) * 8) = o;
}

// ---- h0 fp32 -> bf16 row-major into h buffer 0 ----
__global__ __launch_bounds__(256) void pack_h(const float* __restrict__ h0,
                                              unsigned short* __restrict__ hp) {
  int i = blockIdx.x * 256 + threadIdx.x;     // 131072
  hp[i] = f2bf(h0[i]);
}

// ---- persistent scan: 256 WGs x 256 thr; wave = gate; Wh in regs (128 VGPR) ----
__global__ __launch_bounds__(256, 1) void lstm_scan(
    const unsigned short* __restrict__ xpk,
    const unsigned short* __restrict__ wip,
    const unsigned short* __restrict__ whp,
    unsigned short* __restrict__ hp,            // [2][128][1024] bf16 row-major
    const float* __restrict__ bias,
    const int*   __restrict__ term,
    const float* __restrict__ c0,
    float* __restrict__ out,
    unsigned int* __restrict__ flags) {

  __shared__ union {
    unsigned short hstage[64][64][8];           // [mt*32+kt][lane][8]  = 64 KB
    struct { float gates[4][2][16][17]; unsigned short hout[32][16]; } e;
  } sm;

  const int fg    = blockIdx.x & 63;
  const int mpair = blockIdx.x >> 6;            // 0..3 (rows mpair*32 .. +32)
  const int tid   = threadIdx.x;
  const int wv    = tid >> 6;                   // gate index 0..3 (i,f,g,o)
  const int lane  = tid & 63;
  const int col   = lane & 15;
  const int fi    = fg * 16 + col;

  // resident Wh fragments for ntile wv*64+fg  (128 VGPRs)
  bf8 wh[32];
  {
    const bf8* whb = reinterpret_cast<const bf8*>(whp) + (size_t)(wv * 64 + fg) * 2048 + lane;
#pragma unroll
    for (int kt = 0; kt < 32; ++kt) wh[kt] = whb[kt * 64];
  }
  const bf8* wib = reinterpret_cast<const bf8*>(wip) + (size_t)(wv * 64 + fg) * 2048 + lane;

  float b4[4];
#pragma unroll
  for (int g = 0; g < 4; ++g) b4[g] = bias[g * F_DIM + fi];

  float c_reg[2];
  {
    int wr0 = wv * 8 + (lane >> 4);
    c_reg[0] = c0[(size_t)(mpair * 32 + wr0)     * F_DIM + fi];
    c_reg[1] = c0[(size_t)(mpair * 32 + wr0 + 4) * F_DIM + fi];
  }

  const int srow0 = mpair * 32 + (lane & 15);   // staging row, mt=0
  const int srow1 = srow0 + 16;                 // staging row, mt=1
  const int scol  = (lane >> 4) << 3;

  float* fc = out + (size_t)T_DIM * B_DIM * F_DIM;
  float* fh = fc + (size_t)B_DIM * F_DIM;

#pragma unroll 1
  for (int t = 0; t < T_DIM; ++t) {
    // ---- wait for all WGs to publish h for this step ----
    if (t > 0) {
      if (wv == 0) {
        unsigned int tgt = (unsigned int)t;
        for (;;) {
          unsigned int f0 = __hip_atomic_load(flags + lane,       __ATOMIC_RELAXED, __HIP_MEMORY_SCOPE_AGENT);
          unsigned int f1 = __hip_atomic_load(flags + 64 + lane,  __ATOMIC_RELAXED, __HIP_MEMORY_SCOPE_AGENT);
          unsigned int f2 = __hip_atomic_load(flags + 128 + lane, __ATOMIC_RELAXED, __HIP_MEMORY_SCOPE_AGENT);
          unsigned int f3 = __hip_atomic_load(flags + 192 + lane, __ATOMIC_RELAXED, __HIP_MEMORY_SCOPE_AGENT);
          bool ok = (f0 >= tgt) & (f1 >= tgt) & (f2 >= tgt) & (f3 >= tgt);
          if (__all(ok)) break;
          __builtin_amdgcn_s_sleep(1);
        }
      }
      __syncthreads();
    }

    // ---- stage h_t into LDS (termination-masked), coherent 8B loads ----
    const unsigned short* hb = hp + (size_t)(t & 1) * 131072;
    const int trm0 = term[t * B_DIM + srow0];
    const int trm1 = term[t * B_DIM + srow1];
#pragma unroll
    for (int i = 0; i < 16; ++i) {
      int g2 = wv + 4 * i;                      // 0..63 = mt*32+kt
      int mt = g2 >> 5, kt = g2 & 31;
      int row = mt ? srow1 : srow0;
      int msk = mt ? trm1 : trm0;
      const u64* src = reinterpret_cast<const u64*>(hb + (size_t)row * F_DIM + kt * 32 + scol);
      union { u64 q[2]; bf8 v; } u;
      u.q[0] = msk ? 0ull : __hip_atomic_load(const_cast<u64*>(src),     __ATOMIC_RELAXED, __HIP_MEMORY_SCOPE_AGENT);
      u.q[1] = msk ? 0ull : __hip_atomic_load(const_cast<u64*>(src) + 1, __ATOMIC_RELAXED, __HIP_MEMORY_SCOPE_AGENT);
      *reinterpret_cast<bf8*>(&sm.hstage[g2][lane][0]) = u.v;
    }

    // ---- x @ Wi (plain cached loads; overlaps staging latency) ----
    f32x4 a0 = {0, 0, 0, 0}, a1 = {0, 0, 0, 0};
    const bf8* xb = reinterpret_cast<const bf8*>(xpk) + (size_t)t * 16384 + lane;
#pragma unroll
    for (int kt = 0; kt < 32; ++kt) {
      bf8 wiF = wib[kt * 64];
      bf8 x0 = xb[(kt * 8 + mpair * 2 + 0) * 64];
      bf8 x1 = xb[(kt * 8 + mpair * 2 + 1) * 64];
      a0 = __builtin_amdgcn_mfma_f32_16x16x32_bf16(x0, wiF, a0, 0, 0, 0);
      a1 = __builtin_amdgcn_mfma_f32_16x16x32_bf16(x1, wiF, a1, 0, 0, 0);
    }
    __syncthreads();  // staging complete

    // ---- h @ Wh from LDS, weights in registers ----
#pragma unroll
    for (int kt = 0; kt < 32; ++kt) {
      bf8 h0 = *reinterpret_cast<const bf8*>(&sm.hstage[kt][lane][0]);
      bf8 h1 = *reinterpret_cast<const bf8*>(&sm.hstage[32 + kt][lane][0]);
      a0 = __builtin_amdgcn_mfma_f32_16x16x32_bf16(h0, wh[kt], a0, 0, 0, 0);
      a1 = __builtin_amdgcn_mfma_f32_16x16x32_bf16(h1, wh[kt], a1, 0, 0, 0);
    }
    __syncthreads();  // LDS reads done -> safe to alias

    // ---- gate exchange ----
#pragma unroll
    for (int r = 0; r < 4; ++r) {
      sm.e.gates[wv][0][(lane >> 4) * 4 + r][col] = a0[r];
      sm.e.gates[wv][1][(lane >> 4) * 4 + r][col] = a1[r];
    }
    __syncthreads();

    // ---- epilogue: each wave owns 8 rows (2 cells/lane) ----
    unsigned short* hnext = hp + (size_t)((t + 1) & 1) * 131072;
#pragma unroll
    for (int c2 = 0; c2 < 2; ++c2) {
      int wr = wv * 8 + c2 * 4 + (lane >> 4);
      int mt = wr >> 4, rr = wr & 15;
      int bg = mpair * 32 + wr;
      int trm = term[t * B_DIM + bg];
      float vi = sm.e.gates[0][mt][rr][col] + b4[0];
      float vf = sm.e.gates[1][mt][rr][col] + b4[1];
      float vg = sm.e.gates[2][mt][rr][col] + b4[2];
      float vo = sm.e.gates[3][mt][rr][col] + b4[3];
      float cp = trm ? 0.f : c_reg[c2];
      float cn = sigm(vf) * cp + sigm(vi) * tanh_(vg);
      float hn = sigm(vo) * tanh_(cn);
      c_reg[c2] = cn;
      out[((size_t)t * B_DIM + bg) * F_DIM + fi] = hn;
      sm.e.hout[wr][col] = f2bf(hn);
      if (t == T_DIM - 1) {
        fc[(size_t)bg * F_DIM + fi] = cn;
        fh[(size_t)bg * F_DIM + fi] = hn;
      }
    }
    __syncthreads();

    // ---- wave0 publishes h (16B coherent stores) + flag ----
    if (wv == 0) {
      int r = lane >> 1, hh = lane & 1;
      union { u64 q[2]; bf8 v; } u;
      u.v = *reinterpret_cast<const bf8*>(&sm.e.hout[r][hh * 8]);
      u64* dst = reinterpret_cast<u64*>(hnext + (size_t)(mpair * 32 + r) * F_DIM + fg * 16 + hh * 8);
      __hip_atomic_store(dst,     u.q[0], __ATOMIC_RELAXED, __HIP_MEMORY_SCOPE_AGENT);
      __hip_atomic_store(dst + 1, u.q[1], __ATOMIC_RELAXED, __HIP_MEMORY_SCOPE_AGENT);
      asm volatile("s_waitcnt vmcnt(0)" ::: "memory");
      if (lane == 0)
        __hip_atomic_store(flags + blockIdx.x, (unsigned int)(t + 1),
                           __ATOMIC_RELAXED, __HIP_MEMORY_SCOPE_AGENT);
    }
  }
}

extern "C" void kernel_launch(void* const* d_in, const int* in_sizes, int n_in,
                              void* d_out, int out_size, void* d_ws, size_t ws_size,
                              hipStream_t stream) {
  const float* x    = (const float*)d_in[0];
  const int*   term = (const int*)d_in[1];
  const float* c0   = (const float*)d_in[2];
  const float* h0   = (const float*)d_in[3];
  const float* Wi   = (const float*)d_in[4];
  const float* Wh   = (const float*)d_in[5];
  const float* bias = (const float*)d_in[6];
  float* out = (float*)d_out;
  char*  ws  = (char*)d_ws;

  if (ws_size < WS_NEED) return;

  unsigned int*   flags = (unsigned int*)(ws + OFF_FLAGS);
  unsigned short* wip   = (unsigned short*)(ws + OFF_WIP);
  unsigned short* whp   = (unsigned short*)(ws + OFF_WHP);
  unsigned short* xpk   = (unsigned short*)(ws + OFF_XPK);
  unsigned short* hp    = (unsigned short*)(ws + OFF_HP);

  hipMemsetAsync(flags, 0, 4096, stream);
  pack_w<<<dim3(4096),  dim3(256), 0, stream>>>(Wi, Wh, wip, whp);
  pack_x<<<dim3(16384), dim3(256), 0, stream>>>(x, xpk);
  pack_h<<<dim3(512),   dim3(256), 0, stream>>>(h0, hp);
  lstm_scan<<<dim3(NWGS), dim3(256), 0, stream>>>(xpk, wip, whp, hp, bias, term, c0, out, flags);
}